// Round 4
// baseline (222.145 us; speedup 1.0000x reference)
//
#include <hip/hip_runtime.h>

typedef unsigned short u16;
typedef __bf16 bf16x8 __attribute__((ext_vector_type(8)));
typedef float f32x4 __attribute__((ext_vector_type(4)));

__device__ __forceinline__ u16 f2bf(float f) {
    unsigned u = __builtin_bit_cast(unsigned, f);
    u += 0x7fffu + ((u >> 16) & 1u);
    return (u16)(u >> 16);
}

#define GLDS16(g, l) __builtin_amdgcn_global_load_lds( \
    (const __attribute__((address_space(1))) void*)(g), \
    (__attribute__((address_space(3))) void*)(l), 16, 0, 0)

#define QK_SCALE 0.044194173824159216f

// ---------------------------------------------------------------------------
// Weight conversion + rsum zero-init.
// ---------------------------------------------------------------------------
__global__ __launch_bounds__(256) void convert_kernel(
    const float* __restrict__ Wq, const float* __restrict__ Wk,
    const float* __restrict__ Wv, const float* __restrict__ Wp,
    const float* __restrict__ bq, const float* __restrict__ bk,
    const float* __restrict__ bv,
    u16* __restrict__ Wqkv, u16* __restrict__ Wpb, float* __restrict__ bqkv,
    float* __restrict__ rsum)
{
    int idx = blockIdx.x * 256 + threadIdx.x;
    if (idx < 786432) {
        int which = idx >> 18;
        int off   = idx & 262143;
        if (which == 0)
            Wqkv[idx] = f2bf(Wq[off] * QK_SCALE);
        else
            Wqkv[idx] = f2bf(((which == 1) ? Wk : Wv)[off]);
    } else {
        int off = idx - 786432;
        Wpb[off] = f2bf(Wp[off]);
    }
    if (idx < 1536) {
        float bvv = (idx < 512) ? bq[idx] * QK_SCALE
                  : (idx < 1024) ? bk[idx & 511] : bv[idx & 511];
        bqkv[idx] = bvv;
    }
    if (idx < 16384) rsum[idx] = 0.f;
}

// ---------------------------------------------------------------------------
// GroupNorm stats.
// ---------------------------------------------------------------------------
__global__ __launch_bounds__(256) void gn_stats(
    const float* __restrict__ x, float2* __restrict__ stats)
{
    const int g = blockIdx.x, b = blockIdx.y, tid = threadIdx.x;
    const float* xg = x + ((size_t)b * 512 + (size_t)g * 16) * 1024;

    float s = 0.f, s2 = 0.f;
    const float4* x4 = (const float4*)xg;
    #pragma unroll 4
    for (int i = tid; i < 4096; i += 256) {
        float4 v = x4[i];
        s  += v.x + v.y + v.z + v.w;
        s2 += v.x * v.x + v.y * v.y + v.z * v.z + v.w * v.w;
    }
    #pragma unroll
    for (int off = 32; off; off >>= 1) {
        s  += __shfl_down(s, off);
        s2 += __shfl_down(s2, off);
    }
    __shared__ float rs[4], rs2[4];
    const int w = tid >> 6;
    if ((tid & 63) == 0) { rs[w] = s; rs2[w] = s2; }
    __syncthreads();
    if (tid == 0) {
        float S  = rs[0] + rs[1] + rs[2] + rs[3];
        float S2 = rs2[0] + rs2[1] + rs2[2] + rs2[3];
        float mean = S * (1.f / 16384.f);
        float var  = S2 * (1.f / 16384.f) - mean * mean;
        stats[b * 32 + g] = make_float2(mean, rsqrtf(var + 1e-5f));
    }
}

// ---------------------------------------------------------------------------
// GroupNorm apply + transpose: x [B,C,T] fp32 -> ht [B,T,C] bf16.
// ---------------------------------------------------------------------------
__global__ __launch_bounds__(256) void gn_apply(
    const float* __restrict__ x, const float* __restrict__ gamma,
    const float* __restrict__ beta, const float2* __restrict__ stats,
    u16* __restrict__ ht)
{
    const int tc = blockIdx.x, b = blockIdx.y, tid = threadIdx.x;
    const int t0 = tc * 32;

    __shared__ float2 st[32];
    __shared__ float ga[512], be[512];
    __shared__ __align__(16) u16 tile[512 * 32];

    if (tid < 32) st[tid] = stats[b * 32 + tid];
    for (int c = tid; c < 512; c += 256) { ga[c] = gamma[c]; be[c] = beta[c]; }
    __syncthreads();

    #pragma unroll
    for (int pass = 0; pass < 16; pass++) {
        const int c = pass * 32 + (tid >> 3);
        const int f = tid & 7;
        float4 v = *(const float4*)(x + ((size_t)(b * 512 + c)) * 1024 + t0 + f * 4);
        float2 s = st[c >> 4];
        float sc = s.y * ga[c];
        float sh = be[c] - s.x * sc;
        ushort4 hv = {f2bf(v.x * sc + sh), f2bf(v.y * sc + sh),
                      f2bf(v.z * sc + sh), f2bf(v.w * sc + sh)};
        const int slot = f ^ (c & 7) ^ ((c >> 3) & 7);
        *(ushort4*)(tile + c * 32 + slot * 4) = hv;
    }
    __syncthreads();

    #pragma unroll
    for (int p = 0; p < 8; p++) {
        const int t = p * 4 + (tid >> 6);
        const int l = tid & 63;
        u16 tmp[8];
        #pragma unroll
        for (int e = 0; e < 8; e++) {
            const int c = l * 8 + e;
            const int slot = (t >> 2) ^ (c & 7) ^ ((c >> 3) & 7);
            tmp[e] = tile[c * 32 + slot * 4 + (t & 3)];
        }
        *(uint4*)(ht + ((size_t)b * 1024 + t0 + t) * 512 + l * 8) = *(uint4*)tmp;
    }
}

// ---------------------------------------------------------------------------
// Pipelined NT GEMM: C[m][n] = sum_k A[m][k]*B[n][k], both k-contiguous.
// BM=256, BN=128, BK=64; 512 thr = 8 waves (4M x 2N), wave tile 64x64,
// 16x16x32 bf16 MFMA, acc[4][4] f32x4.
// Schedule (T3+T4): 3 LDS K-tile buffers (144 KB), stage lead = 2 tiles,
// counted s_waitcnt vmcnt(6) at tile top (drains to 0 only on last tile),
// ONE raw s_barrier per K-tile, body split into 2 ks-phases each
// {3 GLDS prefetch | 8 ds_read_b128 | setprio(1) 16 MFMA setprio(0)}.
// NO sched_barrier (m141: order-pinning regresses).  Granule-XOR LDS
// swizzle (slot = chunk ^ (row&7)), GLDS-compatible.
// Softmax fold: MODE1 stores exp(s) + atomics bf16-rounded row sums into
// rsum; MODE2 scales by 1/rsum.
// MODE 0: qkv (q,k [B,T,C] direct scalar; v [B,C,T] LDS-transpose) +bias
// MODE 1: exp(scores)[b][t=n][s=m] LDS-transpose (+rsum via fo)
// MODE 2: h2[b][t=n][c=m] LDS-transpose (rsum in via xres)
// MODE 3: fp32 out[B,C,T] = acc + bias[n] + x, LDS-transpose
// ---------------------------------------------------------------------------
template <int MODE>
__global__ __launch_bounds__(512, 2) void gemm_nt(
    const u16* __restrict__ A, const u16* __restrict__ B,
    size_t strideA, size_t strideB, int lda, int ldb, int K,
    u16* __restrict__ o0, u16* __restrict__ o1, u16* __restrict__ o2,
    float* __restrict__ fo, const float* __restrict__ bias,
    const float* __restrict__ xres)
{
    __shared__ __align__(16) u16 smem[73728];   // 144 KB
    u16* As = smem;                  // 3 x 16384 elems (256x64)
    u16* Bs = smem + 49152;          // 3 x  8192 elems (128x64)

    const int tid  = threadIdx.x;
    const int lane = tid & 63;
    const int wave = tid >> 6;
    const int wm   = (wave & 3) * 64;
    const int wn   = (wave >> 2) * 64;

    // XCD-chunked bijective remap (all grids % 8 == 0)
    const int gx = gridDim.x, gy = gridDim.y;
    int f = blockIdx.x + gx * (blockIdx.y + gy * blockIdx.z);
    const int nwg = gx * gy * (int)gridDim.z;
    f = (f & 7) * (nwg >> 3) + (f >> 3);
    const int bx  = f % gx;
    const int byz = f / gx;
    const int by  = byz % gy;
    const int b   = byz / gy;

    const u16* Ab = A + (size_t)b * strideA + (size_t)by * 256 * lda;
    const u16* Bb = B + (size_t)b * strideB + (size_t)bx * 128 * ldb;

    // staging: unit = 64 rows x 64 cols = 8 KB = 512 thr x 1 GLDS16.
    const int srow = tid >> 3;            // 0..63
    const int sc   = tid & 7;             // LDS granule slot
    const int scg  = sc ^ (srow & 7);     // swizzled source granule

    const u16* aSrc[4]; int aDst[4];
    #pragma unroll
    for (int u = 0; u < 4; u++) {
        aSrc[u] = Ab + (size_t)(u * 64 + srow) * lda + scg * 8;
        aDst[u] = (u * 64 + srow) * 64 + sc * 8;
    }
    const u16* bSrc[2]; int bDst[2];
    #pragma unroll
    for (int u = 0; u < 2; u++) {
        bSrc[u] = Bb + (size_t)(u * 64 + srow) * ldb + scg * 8;
        bDst[u] = (u * 64 + srow) * 64 + sc * 8;
    }

    // frag read offsets (16x16x32: row = base + (lane&15), kgran = lane>>4)
    const int l15 = lane & 15, lh = lane >> 4, rx = lane & 7;
    int aOff[4][2], bOff[4][2];
    #pragma unroll
    for (int i = 0; i < 4; i++)
        #pragma unroll
        for (int ks = 0; ks < 2; ks++) {
            const int slot = ((ks << 2) + lh) ^ rx;
            aOff[i][ks] = (wm + i * 16 + l15) * 64 + slot * 8;
            bOff[i][ks] = (wn + i * 16 + l15) * 64 + slot * 8;
        }

    f32x4 acc[4][4] = {};
    const int NT = K >> 6;

    // prologue: stage tiles 0 and 1 (6 loads each)
    #pragma unroll
    for (int u = 0; u < 4; u++) GLDS16(aSrc[u], As + aDst[u]);
    #pragma unroll
    for (int u = 0; u < 2; u++) GLDS16(bSrc[u], Bs + bDst[u]);
    #pragma unroll
    for (int u = 0; u < 4; u++) GLDS16(aSrc[u] + 64, As + 16384 + aDst[u]);
    #pragma unroll
    for (int u = 0; u < 2; u++) GLDS16(bSrc[u] + 64, Bs + 8192 + bDst[u]);

    int cbuf = 0, sbuf = 2;
    for (int t = 0; t < NT; ++t) {
        // counted wait: newest 6 loads (= tile t+1's stage) may stay in flight
        if (t == NT - 1) asm volatile("s_waitcnt vmcnt(0)" ::: "memory");
        else             asm volatile("s_waitcnt vmcnt(6)" ::: "memory");
        __builtin_amdgcn_s_barrier();

        const u16* Ac = As + cbuf * 16384;
        const u16* Bc = Bs + cbuf * 8192;
        u16* Asb = As + sbuf * 16384;
        u16* Bsb = Bs + sbuf * 8192;
        const int ko = (t + 2) * 64;
        const bool pf = (t + 2 < NT);

        // ---- phase 0: prefetch half of tile t+2, compute ks=0 ----
        if (pf) {
            GLDS16(aSrc[0] + ko, Asb + aDst[0]);
            GLDS16(aSrc[1] + ko, Asb + aDst[1]);
            GLDS16(bSrc[0] + ko, Bsb + bDst[0]);
        }
        {
            bf16x8 af[4], bfr[4];
            #pragma unroll
            for (int i = 0; i < 4; i++) {
                af[i]  = *(const bf16x8*)(Ac + aOff[i][0]);
                bfr[i] = *(const bf16x8*)(Bc + bOff[i][0]);
            }
            __builtin_amdgcn_s_setprio(1);
            #pragma unroll
            for (int mi = 0; mi < 4; mi++)
                #pragma unroll
                for (int nj = 0; nj < 4; nj++)
                    acc[mi][nj] = __builtin_amdgcn_mfma_f32_16x16x32_bf16(
                        af[mi], bfr[nj], acc[mi][nj], 0, 0, 0);
            __builtin_amdgcn_s_setprio(0);
        }
        // ---- phase 1: prefetch other half, compute ks=1 ----
        if (pf) {
            GLDS16(aSrc[2] + ko, Asb + aDst[2]);
            GLDS16(aSrc[3] + ko, Asb + aDst[3]);
            GLDS16(bSrc[1] + ko, Bsb + bDst[1]);
        }
        {
            bf16x8 af[4], bfr[4];
            #pragma unroll
            for (int i = 0; i < 4; i++) {
                af[i]  = *(const bf16x8*)(Ac + aOff[i][1]);
                bfr[i] = *(const bf16x8*)(Bc + bOff[i][1]);
            }
            __builtin_amdgcn_s_setprio(1);
            #pragma unroll
            for (int mi = 0; mi < 4; mi++)
                #pragma unroll
                for (int nj = 0; nj < 4; nj++)
                    acc[mi][nj] = __builtin_amdgcn_mfma_f32_16x16x32_bf16(
                        af[mi], bfr[nj], acc[mi][nj], 0, 0, 0);
            __builtin_amdgcn_s_setprio(0);
        }

        cbuf = (cbuf == 2) ? 0 : cbuf + 1;
        sbuf = (sbuf == 2) ? 0 : sbuf + 1;
    }

    const int N0 = bx * 128;
    const int M0 = by * 256;

    if (MODE == 0 && N0 < 1024) {
        // q or k: [B,T,C] direct scalar stores (block covers full 128-n span
        // per output row aggregate -> no L2 RMW).  C/D: col=lane&15,
        // row=(lane>>4)*4+reg.
        u16* dst = (N0 < 512) ? o0 : o1;
        const int nn0 = N0 & 511;
        #pragma unroll
        for (int nj = 0; nj < 4; nj++) {
            const int n = wn + nj * 16 + l15;
            const float bv = bias[N0 + n];
            #pragma unroll
            for (int mi = 0; mi < 4; mi++) {
                const int mq = M0 + wm + mi * 16 + lh * 4;
                const size_t base = ((size_t)b * 1024 + mq) * 512 + nn0 + n;
                dst[base]        = f2bf(acc[mi][nj][0] + bv);
                dst[base + 512]  = f2bf(acc[mi][nj][1] + bv);
                dst[base + 1024] = f2bf(acc[mi][nj][2] + bv);
                dst[base + 1536] = f2bf(acc[mi][nj][3] + bv);
            }
        }
    } else if (MODE != 3) {
        // bf16 [n][m] tile (64 KB) in LDS, then 512B-row coalesced stores.
        __syncthreads();
        float rinv_[4];
        if (MODE == 2) {
            #pragma unroll
            for (int nj = 0; nj < 4; nj++)
                rinv_[nj] = 1.0f / xres[(size_t)b * 1024 + N0 + wn + nj * 16 + l15];
        }
        #pragma unroll
        for (int mi = 0; mi < 4; mi++) {
            const int mq = wm + mi * 16 + lh * 4;     // multiple of 4
            #pragma unroll
            for (int nj = 0; nj < 4; nj++) {
                const int n = wn + nj * 16 + l15;
                float a0 = acc[mi][nj][0], a1 = acc[mi][nj][1];
                float a2 = acc[mi][nj][2], a3 = acc[mi][nj][3];
                if (MODE == 0) {
                    const float bv = bias[N0 + n];
                    a0 += bv; a1 += bv; a2 += bv; a3 += bv;
                }
                if (MODE == 1) {
                    a0 = __expf(a0); a1 = __expf(a1);
                    a2 = __expf(a2); a3 = __expf(a3);
                }
                if (MODE == 2) {
                    a0 *= rinv_[nj]; a1 *= rinv_[nj];
                    a2 *= rinv_[nj]; a3 *= rinv_[nj];
                }
                ushort4 hv = {f2bf(a0), f2bf(a1), f2bf(a2), f2bf(a3)};
                *(ushort4*)((char*)smem + n * 512 +
                            (((mq >> 3) ^ (n & 31)) << 4) + ((mq >> 2) & 1) * 8) = hv;
            }
        }
        __syncthreads();
        #pragma unroll
        for (int p = 0; p < 8; p++) {
            const int n  = p * 16 + (tid >> 5);
            const int gi = tid & 31;
            uint4 v4 = *(const uint4*)((char*)smem + n * 512 +
                                       ((gi ^ (n & 31)) << 4));
            u16* dst;
            if (MODE == 0)      dst = o2 + ((size_t)b * 512 + (N0 - 1024) + n) * 1024 + M0;
            else if (MODE == 1) dst = o0 + ((size_t)b * 1024 + N0 + n) * 1024 + M0;
            else                dst = o0 + ((size_t)b * 1024 + N0 + n) * 512 + M0;
            *(uint4*)(dst + gi * 8) = v4;
            if (MODE == 1) {
                unsigned wd_[4] = {v4.x, v4.y, v4.z, v4.w};
                float rsm = 0.f;
                #pragma unroll
                for (int q = 0; q < 4; q++)
                    rsm += __builtin_bit_cast(float, wd_[q] << 16)
                         + __builtin_bit_cast(float, wd_[q] & 0xffff0000u);
                #pragma unroll
                for (int off = 1; off < 32; off <<= 1)
                    rsm += __shfl_xor(rsm, off);
                if (gi == 0)
                    atomicAdd(fo + ((size_t)b * 1024 + N0 + n), rsm);
            }
        }
    } else {
        // fp32 [n:128][m:256] tile (128 KB), slot16 swizzle; +bias +residual
        __syncthreads();
        float* smf = (float*)smem;
        #pragma unroll
        for (int mi = 0; mi < 4; mi++) {
            const int mq = wm + mi * 16 + lh * 4;
            #pragma unroll
            for (int nj = 0; nj < 4; nj++) {
                const int n = wn + nj * 16 + l15;
                float4 v4 = {acc[mi][nj][0], acc[mi][nj][1],
                             acc[mi][nj][2], acc[mi][nj][3]};
                *(float4*)((char*)smf + n * 1024 +
                           (((mq >> 2) ^ (n & 63)) << 4)) = v4;
            }
        }
        __syncthreads();
        #pragma unroll
        for (int p = 0; p < 16; p++) {
            const int n  = p * 8 + (tid >> 6);
            const int gi = tid & 63;
            float4 v4 = *(const float4*)((char*)smf + n * 1024 +
                                         ((gi ^ (n & 63)) << 4));
            const size_t off = ((size_t)b * 512 + N0 + n) * 1024 + M0 + gi * 4;
            const float bv = bias[N0 + n];
            const float4 xv = *(const float4*)(xres + off);
            float4 ov = {v4.x + bv + xv.x, v4.y + bv + xv.y,
                         v4.z + bv + xv.z, v4.w + bv + xv.w};
            *(float4*)(fo + off) = ov;
        }
    }
}

// ---------------------------------------------------------------------------
extern "C" void kernel_launch(void* const* d_in, const int* in_sizes, int n_in,
                              void* d_out, int out_size, void* d_ws, size_t ws_size,
                              hipStream_t stream)
{
    const float* x     = (const float*)d_in[0];
    const float* gamma = (const float*)d_in[1];
    const float* beta  = (const float*)d_in[2];
    const float* Wq    = (const float*)d_in[3];
    const float* bq    = (const float*)d_in[4];
    const float* Wk    = (const float*)d_in[5];
    const float* bk    = (const float*)d_in[6];
    const float* Wv    = (const float*)d_in[7];
    const float* bv    = (const float*)d_in[8];
    const float* Wp    = (const float*)d_in[9];
    const float* bp    = (const float*)d_in[10];

    char* ws = (char*)d_ws;
    u16*   Wqkv   = (u16*)(ws + 0);           //  1,572,864 B
    u16*   Wpb    = (u16*)(ws + 1572864);     //    524,288 B
    float* bqkv   = (float*)(ws + 2097152);   //      8,192 B
    u16*   ht     = (u16*)(ws + 2105344);     // 16,777,216 B (reused as h2)
    u16*   kt     = (u16*)(ws + 18882560);    // 16,777,216 B
    u16*   vv     = (u16*)(ws + 35659776);    // 16,777,216 B
    u16*   scores = (u16*)(ws + 52436992);    // 33,554,432 B bf16 (holds exp(s))
    u16*   qt  = (u16*)d_out;   // scratch: q [B,T,C] bf16 (first 16.8MB)
    float2* stats = (float2*)((char*)d_out + 16777216);  // 4KB scratch
    float* rsum   = (float*)((char*)d_out + 16781312);   // 64KB scratch
    u16*   h2  = ht;
    float* out = (float*)d_out;

    convert_kernel<<<4096, 256, 0, stream>>>(Wq, Wk, Wv, Wp, bq, bk, bv,
                                             Wqkv, Wpb, bqkv, rsum);
    gn_stats<<<dim3(32, 16), 256, 0, stream>>>(x, stats);
    gn_apply<<<dim3(32, 16), 256, 0, stream>>>(x, gamma, beta, stats, ht);

    // GEMM1 qkv: M=1024(T) N=1536(3C) K=512 ; 768 blocks = 3 full CU rounds
    gemm_nt<0><<<dim3(12, 4, 16), 512, 0, stream>>>(
        ht, Wqkv, 524288, 0, 512, 512, 512,
        qt, kt, vv, nullptr, bqkv, nullptr);

    // GEMM2 scores: M=1024(S) N=1024(T) K=512 ; 512 blocks; P'=exp(s), rsum
    gemm_nt<1><<<dim3(8, 4, 16), 512, 0, stream>>>(
        kt, qt, 524288, 524288, 512, 512, 512,
        scores, nullptr, nullptr, rsum, nullptr, nullptr);

    // GEMM3 pv: M=512(C) N=1024(T) K=1024(S) ; 256 blocks; scale 1/rsum
    gemm_nt<2><<<dim3(8, 2, 16), 512, 0, stream>>>(
        vv, scores, 524288, 1048576, 1024, 1024, 1024,
        h2, nullptr, nullptr, nullptr, nullptr, rsum);

    // GEMM4 proj+residual: M=1024(T) N=512(C) K=512 ; 256 blocks
    gemm_nt<3><<<dim3(4, 4, 16), 512, 0, stream>>>(
        h2, Wpb, 524288, 0, 512, 512, 512,
        nullptr, nullptr, nullptr, out, bp, x);
}